// Round 6
// baseline (381.889 us; speedup 1.0000x reference)
//
#include <hip/hip_runtime.h>
#include <stdint.h>
#include <math.h>

#define BT   65536
#define H    4
#define K    512
#define DH   256
#define EPSN 1e-12f
#define EPSL 1e-10f
#define TAU  0.03f
#define CTH  0.970446f      // exp(-TAU)
#define CMAX 16
#define NREP 8              // avg_probs accumulator replicas

typedef short bf16x8 __attribute__((ext_vector_type(8)));
typedef float f32x4  __attribute__((ext_vector_type(4)));

__device__ inline unsigned short f2bf(float f) {
  uint32_t u = __builtin_bit_cast(uint32_t, f);
  u += 0x7fffu + ((u >> 16) & 1u);
  return (unsigned short)(u >> 16);
}

// ---------------------------------------------------------------------------
// ws layout (float slots):
//   en_f    : [H][K][DH] fp32 normalized    524288
//   en_b    : [H][K][DH] bf16 normalized    131072 slots
//   avgp    : [NREP][H*K]                   16384
//   meta_ws : [BT*H] int (cnt<<16 | gcol)   262144
//   norms_ws: [BT*H] float                  262144
//   cand_ws : [BT*H][CMAX] u16              1048576 slots (4 MiB)
// total ~9 MiB
// ---------------------------------------------------------------------------

__global__ __launch_bounds__(256) void vq_prep(const float* __restrict__ emb,
                                               float* __restrict__ en_f,
                                               unsigned short* __restrict__ en_b,
                                               float* __restrict__ avgp) {
  const int hk = blockIdx.x;        // h*K + k
  const int t  = threadIdx.x;       // d
  const float v = emb[(size_t)hk * DH + t];
  float s = v * v;
#pragma unroll
  for (int m = 1; m < 64; m <<= 1) s += __shfl_xor(s, m);
  __shared__ float wsum[4];
  if ((t & 63) == 0) wsum[t >> 6] = s;
  __syncthreads();
  const float tot = wsum[0] + wsum[1] + wsum[2] + wsum[3];
  const float n   = fmaxf(sqrtf(tot), EPSN);
  const float vn  = v / n;
  en_f[(size_t)hk * DH + t] = vn;
  en_b[(size_t)hk * DH + t] = f2bf(vn);
  if (t < NREP) avgp[t * (H * K) + hk] = 0.0f;
}

// Block: 64 b-rows x 512 codes for one h. 512 threads = 8 waves.
// Wave w owns codes [64w, 64w+64): acc[4][4]; code = 64w+16mi+4kg+q,
// zrow = 16ni + arow. Ends after avg_probs; tail work moves to vq_post.
__global__ __launch_bounds__(512, 4) void vq_main(
    const float* __restrict__ z_e, const float* __restrict__ scales,
    const unsigned short* __restrict__ en_b,
    float* __restrict__ avgp, int* __restrict__ meta_ws,
    float* __restrict__ norms_ws, unsigned short* __restrict__ cand_ws) {
  const int h     = blockIdx.y;
  const int bbase = blockIdx.x * 64;
  const int t     = threadIdx.x;
  const int w     = t >> 6;
  const int l     = t & 63;
  const int arow  = l & 15;
  const int kg    = l >> 4;                      // 0..3

  __shared__ unsigned short a_lds[64 * 256];     // 32 KiB z bf16, XOR-swizzled
  __shared__ float wredm[8][64];                 // per-wave max
  __shared__ float wred2[8][64];                 // per-wave 2nd max
  __shared__ float wreds[8][64];                 // per-wave exp-sum
  __shared__ int   wcols[8][64];
  __shared__ __align__(16) unsigned short cand[64][CMAX];
  __shared__ float gmx[64];
  __shared__ int   gcol[64];
  __shared__ float Srec[64];
  __shared__ int   flagd[64];
  __shared__ int   cnt[64];

  // ---- stage: load z row (8 lanes/row), L2-normalize (ref), bf16 -> LDS ----
  {
    const int row = t >> 3;                      // 0..63
    const int c8  = t & 7;
    const float* zp = z_e + (size_t)(bbase + row) * (H * DH) + h * DH;
    float4 q[8];
    float ss = 0.0f;
#pragma unroll
    for (int j = 0; j < 8; j++) {
      q[j] = *(const float4*)(zp + c8 * 4 + j * 32);
      ss += q[j].x * q[j].x + q[j].y * q[j].y + q[j].z * q[j].z + q[j].w * q[j].w;
    }
    ss += __shfl_xor(ss, 1);
    ss += __shfl_xor(ss, 2);
    ss += __shfl_xor(ss, 4);
    const float n   = fmaxf(sqrtf(ss), EPSN);
    const float inv = 1.0f / n;
    if (c8 == 0) norms_ws[(size_t)(bbase + row) * H + h] = n;
    const int swz = (row & 7) << 4;
#pragma unroll
    for (int j = 0; j < 8; j++) {
      const int d = c8 * 4 + j * 32;
      uint2 pk;
      pk.x = (uint32_t)f2bf(q[j].x * inv) | ((uint32_t)f2bf(q[j].y * inv) << 16);
      pk.y = (uint32_t)f2bf(q[j].z * inv) | ((uint32_t)f2bf(q[j].w * inv) << 16);
      *(uint2*)((char*)a_lds + row * 512 + ((d * 2) ^ swz)) = pk;
    }
    if (t < 64) cnt[t] = 0;
  }
  __syncthreads();

  // ---- MFMA GEMM: A = en codes (L2), B = z rows (LDS) ----
  f32x4 acc[4][4];
#pragma unroll
  for (int mi = 0; mi < 4; mi++)
#pragma unroll
    for (int ni = 0; ni < 4; ni++) acc[mi][ni] = (f32x4){0.f, 0.f, 0.f, 0.f};

  const unsigned short* ep =
      en_b + ((size_t)(h * K) + w * 64 + arow) * DH + kg * 8;

#pragma unroll
  for (int ks = 0; ks < 8; ks++) {
    bf16x8 ef[4];
#pragma unroll
    for (int mi = 0; mi < 4; mi++)
      ef[mi] = *(const bf16x8*)(ep + (size_t)mi * 16 * DH + ks * 32);
    bf16x8 zf[4];
#pragma unroll
    for (int ni = 0; ni < 4; ni++) {
      const int rr = ni * 16 + arow;
      const int kb = (ks * 64) | (kg * 16);
      zf[ni] = *(const bf16x8*)((const char*)a_lds + rr * 512 +
                                (kb ^ ((rr & 7) << 4)));
    }
#pragma unroll
    for (int mi = 0; mi < 4; mi++)
#pragma unroll
      for (int ni = 0; ni < 4; ni++)
        acc[mi][ni] = __builtin_amdgcn_mfma_f32_16x16x32_bf16(ef[mi], zf[ni],
                                                              acc[mi][ni], 0, 0, 0);
  }

  // ---- pass 1: e = exp(sc*logit) in place; per-lane {max, 2nd-max, col, sum} ----
  const float sc = scales[h];
  float m1[4], m2[4], es[4]; int c1[4];
#pragma unroll
  for (int ni = 0; ni < 4; ni++) {
    m1[ni] = 0.0f; m2[ni] = 0.0f; es[ni] = 0.0f; c1[ni] = 1 << 30;
  }
#pragma unroll
  for (int mi = 0; mi < 4; mi++)
#pragma unroll
    for (int ni = 0; ni < 4; ni++)
#pragma unroll
      for (int q = 0; q < 4; q++) {
        const float e = __expf(sc * acc[mi][ni][q]);
        acc[mi][ni][q] = e;
        const int code = w * 64 + mi * 16 + kg * 4 + q;
        if (e > m1[ni]) { m2[ni] = m1[ni]; m1[ni] = e; c1[ni] = code; }
        else            m2[ni] = fmaxf(m2[ni], e);
        es[ni] += e;
      }
  // combine over kg (masks 16, 32)
#pragma unroll
  for (int m = 16; m < 64; m <<= 1) {
#pragma unroll
    for (int ni = 0; ni < 4; ni++) {
      const float om1 = __shfl_xor(m1[ni], m);
      const float om2 = __shfl_xor(m2[ni], m);
      const int   oc  = __shfl_xor(c1[ni], m);
      const float nm2 = fmaxf(fmaxf(m2[ni], om2), fminf(m1[ni], om1));
      if (om1 > m1[ni] || (om1 == m1[ni] && oc < c1[ni])) { m1[ni] = om1; c1[ni] = oc; }
      m2[ni] = nm2;
      es[ni] += __shfl_xor(es[ni], m);
    }
  }
  if (kg == 0) {
#pragma unroll
    for (int ni = 0; ni < 4; ni++) {
      const int r = ni * 16 + arow;
      wredm[w][r] = m1[ni];
      wred2[w][r] = m2[ni];
      wcols[w][r] = c1[ni];
      wreds[w][r] = es[ni];
    }
  }
  __syncthreads();
  if (t < 64) {
    float a1 = 0.0f, a2 = 0.0f, s = 0.0f; int c = 1 << 30;
#pragma unroll
    for (int ww = 0; ww < 8; ww++) {
      const float vm = wredm[ww][t];
      const float v2 = wred2[ww][t];
      const int   vc = wcols[ww][t];
      const float n2 = fmaxf(fmaxf(a2, v2), fminf(a1, vm));
      if (vm > a1 || (vm == a1 && vc < c)) { a1 = vm; c = vc; }
      a2 = n2;
      s += wreds[ww][t];
    }
    gmx[t] = a1; gcol[t] = c; Srec[t] = 1.0f / s;
    flagd[t] = (a2 >= a1 * CTH) ? 1 : 0;       // 2nd max within TAU -> refine
  }
  __syncthreads();

  // ---- pass 2: avg_probs (pure fma) + rare candidate scan ----
  {
    float rs[4], th[4]; int fl[4];
#pragma unroll
    for (int ni = 0; ni < 4; ni++) {
      const int r = ni * 16 + arow;
      rs[ni] = Srec[r];
      th[ni] = gmx[r] * CTH;
      fl[ni] = flagd[r];
    }
    float* ap = avgp + (blockIdx.x & (NREP - 1)) * (H * K) + h * K;
#pragma unroll
    for (int mi = 0; mi < 4; mi++)
#pragma unroll
      for (int q = 0; q < 4; q++) {
        float vs = 0.0f;
#pragma unroll
        for (int ni = 0; ni < 4; ni++) vs = fmaf(acc[mi][ni][q], rs[ni], vs);
        vs += __shfl_xor(vs, 1);
        vs += __shfl_xor(vs, 2);
        vs += __shfl_xor(vs, 4);
        vs += __shfl_xor(vs, 8);
        if (arow == 0) atomicAdd(&ap[w * 64 + mi * 16 + kg * 4 + q], vs);
      }
    if (fl[0] | fl[1] | fl[2] | fl[3]) {
#pragma unroll
      for (int mi = 0; mi < 4; mi++)
#pragma unroll
        for (int ni = 0; ni < 4; ni++)
#pragma unroll
          for (int q = 0; q < 4; q++) {
            if (fl[ni] && acc[mi][ni][q] >= th[ni]) {
              const int r = ni * 16 + arow;
              const int p = atomicAdd(&cnt[r], 1);
              if (p < CMAX)
                cand[r][p] = (unsigned short)(w * 64 + mi * 16 + kg * 4 + q);
            }
          }
    }
  }
  __syncthreads();

  // ---- meta write ----
  if (t < 64) {
    int c = cnt[t]; if (c > CMAX) c = CMAX;
    const size_t bh = (size_t)(bbase + t) * H + h;
    meta_ws[bh] = (c << 16) | gcol[t];
    if (c > 1) {
      uint4* dst = (uint4*)(cand_ws + bh * CMAX);
      const uint4* src = (const uint4*)&cand[t][0];
      dst[0] = src[0];
      dst[1] = src[1];
    }
  }
}

// Post: refine flagged rows exactly, compute combined, gather z_q.
// Block: 64 b (all 4 h) = 256 tasks, 256 threads = 4 waves.
__global__ __launch_bounds__(256) void vq_post(
    const float* __restrict__ z_e, const float* __restrict__ emb,
    const float* __restrict__ en_f, const int* __restrict__ meta_ws,
    const float* __restrict__ norms_ws, const unsigned short* __restrict__ cand_ws,
    float* __restrict__ outq, float* __restrict__ out_comb) {
  const int bbase = blockIdx.x * 64;
  const int t     = threadIdx.x;
  const int w     = t >> 6;
  const int l     = t & 63;

  __shared__ int idx_l[64][4];
  __shared__ int cnts[256];

  // phase A: default idx from meta
  {
    const int bl = t >> 2, hh = t & 3;
    const int m  = meta_ws[(size_t)(bbase + bl) * H + hh];
    idx_l[bl][hh] = m & 0xFFFF;
    cnts[t]       = m >> 16;
  }
  __syncthreads();

  // phase B: exact fp32 refine for cnt>1 tasks (wave-cooperative)
  for (int i = 0; i < 64; i++) {
    const int tt = w * 64 + i;
    const int c  = cnts[tt];
    if (c <= 1) continue;
    const int bl = tt >> 2, hh = tt & 3;
    const size_t bh = (size_t)(bbase + bl) * H + hh;
    const float nrm = norms_ws[bh];
    const float4 zq = *(const float4*)(z_e + (size_t)(bbase + bl) * (H * DH) +
                                       hh * DH + l * 4);
    const float zn0 = zq.x / nrm, zn1 = zq.y / nrm,
                zn2 = zq.z / nrm, zn3 = zq.w / nrm;
    float bv = -INFINITY; int bi = 1 << 30;
    for (int j = 0; j < c; j++) {
      const int cd = cand_ws[bh * CMAX + j];
      const float4 eq = *(const float4*)(en_f + ((size_t)(hh * K) + cd) * DH + l * 4);
      float d0 = fmaf(zn0, eq.x, fmaf(zn1, eq.y, fmaf(zn2, eq.z, zn3 * eq.w)));
#pragma unroll
      for (int m = 1; m < 64; m <<= 1) d0 += __shfl_xor(d0, m);
      if (d0 > bv || (d0 == bv && cd < bi)) { bv = d0; bi = cd; }
    }
    if (l == 0) idx_l[bl][hh] = bi;
  }
  __syncthreads();

  // phase C: combined (int32 wraparound), as float
  if (t < 64) {
    uint32_t cv = (uint32_t)idx_l[t][0];
    cv = cv * 512u + (uint32_t)idx_l[t][1];
    cv = cv * 512u + (uint32_t)idx_l[t][2];
    cv = cv * 512u + (uint32_t)idx_l[t][3];
    out_comb[bbase + t] = (float)(int32_t)cv;
  }

  // phase D: z_q gather (raw emb rows), 1 KiB coalesced per task
  for (int i = 0; i < 64; i++) {
    const int tt = w * 64 + i;
    const int bl = tt >> 2, hh = tt & 3;
    const int idx = idx_l[bl][hh];
    const float4 v = *(const float4*)(emb + ((size_t)(hh * K) + idx) * DH + l * 4);
    *(float4*)(outq + (size_t)(bbase + bl) * (H * DH) + hh * DH + l * 4) = v;
  }
}

__global__ __launch_bounds__(256) void vq_perp(const float* __restrict__ avgp,
                                               float* __restrict__ out_perp) {
  const int t = threadIdx.x;
  float sh[H] = {0.f, 0.f, 0.f, 0.f};
  for (int i = t; i < H * K; i += 256) {
    const int h = i >> 9;
    float a = 0.0f;
#pragma unroll
    for (int c = 0; c < NREP; c++) a += avgp[c * (H * K) + i];
    a /= 65536.0f;
    sh[h] += a * logf(a + EPSL);
  }
  __shared__ float red[4][H];
#pragma unroll
  for (int h = 0; h < H; h++) {
    float s = sh[h];
#pragma unroll
    for (int m = 1; m < 64; m <<= 1) s += __shfl_xor(s, m);
    if ((t & 63) == 0) red[t >> 6][h] = s;
  }
  __syncthreads();
  if (t == 0) {
    float p = 0.0f;
#pragma unroll
    for (int h = 0; h < H; h++) {
      const float s = red[0][h] + red[1][h] + red[2][h] + red[3][h];
      p += expf(-s);
    }
    out_perp[0] = p * 0.25f;
  }
}

extern "C" void kernel_launch(void* const* d_in, const int* in_sizes, int n_in,
                              void* d_out, int out_size, void* d_ws, size_t ws_size,
                              hipStream_t stream) {
  const float* z_e    = (const float*)d_in[0];
  const float* emb    = (const float*)d_in[1];
  const float* scales = (const float*)d_in[2];
  float* out = (float*)d_out;

  float*          en_f    = (float*)d_ws;                         // 524288
  unsigned short* en_b    = (unsigned short*)(en_f + (size_t)H * K * DH);
  float*          avgp    = (float*)(en_b + (size_t)H * K * DH);  // 16384
  int*            meta_ws = (int*)(avgp + NREP * H * K);          // 262144
  float*          norms_ws= (float*)(meta_ws + (size_t)BT * H);   // 262144
  unsigned short* cand_ws = (unsigned short*)(norms_ws + (size_t)BT * H);

  hipLaunchKernelGGL(vq_prep, dim3(H * K), dim3(256), 0, stream,
                     emb, en_f, en_b, avgp);
  hipLaunchKernelGGL(vq_main, dim3(BT / 64, H), dim3(512), 0, stream,
                     z_e, scales, en_b, avgp, meta_ws, norms_ws, cand_ws);
  hipLaunchKernelGGL(vq_post, dim3(BT / 64), dim3(256), 0, stream,
                     z_e, emb, en_f, meta_ws, norms_ws, cand_ws,
                     out, out + (size_t)BT * H * DH);
  hipLaunchKernelGGL(vq_perp, dim3(1), dim3(256), 0, stream,
                     avgp, out + (size_t)BT * H * DH + BT);
}

// Round 7
// 297.149 us; speedup vs baseline: 1.2852x; 1.2852x over previous
//
#include <hip/hip_runtime.h>
#include <stdint.h>
#include <math.h>

#define BT   65536
#define H    4
#define K    512
#define DH   256
#define EPSN 1e-12f
#define EPSL 1e-10f
#define TAU  0.03f
#define CTH  0.970446f      // exp(-TAU)
#define CMAX 16
#define NREP 8              // avg_probs accumulator replicas

typedef short bf16x8 __attribute__((ext_vector_type(8)));
typedef float f32x4  __attribute__((ext_vector_type(4)));

__device__ inline unsigned short f2bf(float f) {
  uint32_t u = __builtin_bit_cast(uint32_t, f);
  u += 0x7fffu + ((u >> 16) & 1u);
  return (unsigned short)(u >> 16);
}

// ---------------------------------------------------------------------------
// ws layout (float slots):
//   en_f  : [H][K][DH] fp32 normalized      524288
//   en_b  : [H][K][DH] bf16 normalized      131072 slots
//   avgp  : [NREP][H*K]                     16384
//   idx_ws: [BT][H] int                     262144
// ---------------------------------------------------------------------------

__global__ __launch_bounds__(256) void vq_prep(const float* __restrict__ emb,
                                               float* __restrict__ en_f,
                                               unsigned short* __restrict__ en_b,
                                               float* __restrict__ avgp) {
  const int hk = blockIdx.x;        // h*K + k
  const int t  = threadIdx.x;       // d
  const float v = emb[(size_t)hk * DH + t];
  float s = v * v;
#pragma unroll
  for (int m = 1; m < 64; m <<= 1) s += __shfl_xor(s, m);
  __shared__ float wsum[4];
  if ((t & 63) == 0) wsum[t >> 6] = s;
  __syncthreads();
  const float tot = wsum[0] + wsum[1] + wsum[2] + wsum[3];
  const float n   = fmaxf(sqrtf(tot), EPSN);
  const float vn  = v / n;
  en_f[(size_t)hk * DH + t] = vn;
  en_b[(size_t)hk * DH + t] = f2bf(vn);
  if (t < NREP) avgp[t * (H * K) + hk] = 0.0f;
}

// Block: 64 b-rows x 512 codes for one h. 512 threads = 8 waves.
// Wave w owns codes [64w, 64w+64): acc[4][4]; code = 64w+16mi+4kg+q,
// zrow = 16ni + arow. 64 acc AGPR + ~64 VGPR = 128 unified -> 4 waves/SIMD cap.
__global__ __launch_bounds__(512, 4) void vq_main(
    const float* __restrict__ z_e, const float* __restrict__ emb,
    const float* __restrict__ scales,
    const float* __restrict__ en_f, const unsigned short* __restrict__ en_b,
    float* __restrict__ avgp, int* __restrict__ idx_ws,
    float* __restrict__ outq) {
  const int h     = blockIdx.y;
  const int bbase = blockIdx.x * 64;
  const int t     = threadIdx.x;
  const int w     = t >> 6;
  const int l     = t & 63;
  const int arow  = l & 15;
  const int kg    = l >> 4;                      // 0..3

  __shared__ unsigned short a_lds[64 * 256];     // 32 KiB z bf16, XOR-swizzled
  __shared__ float norms[64];
  __shared__ float wredm[8][64];                 // per-wave max
  __shared__ float wred2[8][64];                 // per-wave 2nd max
  __shared__ float wreds[8][64];                 // per-wave exp-sum
  __shared__ int   wcols[8][64];
  __shared__ __align__(16) unsigned short cand[64][CMAX];
  __shared__ float gmx[64];
  __shared__ int   gcol[64];
  __shared__ float Srec[64];
  __shared__ int   flagd[64];
  __shared__ int   cnt[64];
  __shared__ int   fidx[64];
  __shared__ float avg_lds[512];                 // per-block avg_probs partial

  // ---- stage: load z row (8 lanes/row), L2-normalize (ref), bf16 -> LDS ----
  {
    const int row = t >> 3;                      // 0..63
    const int c8  = t & 7;
    const float* zp = z_e + (size_t)(bbase + row) * (H * DH) + h * DH;
    float4 q[8];
    float ss = 0.0f;
#pragma unroll
    for (int j = 0; j < 8; j++) {
      q[j] = *(const float4*)(zp + c8 * 4 + j * 32);
      ss += q[j].x * q[j].x + q[j].y * q[j].y + q[j].z * q[j].z + q[j].w * q[j].w;
    }
    ss += __shfl_xor(ss, 1);
    ss += __shfl_xor(ss, 2);
    ss += __shfl_xor(ss, 4);
    const float n   = fmaxf(sqrtf(ss), EPSN);
    const float inv = 1.0f / n;
    if (c8 == 0) norms[row] = n;
    const int swz = (row & 7) << 4;
#pragma unroll
    for (int j = 0; j < 8; j++) {
      const int d = c8 * 4 + j * 32;
      uint2 pk;
      pk.x = (uint32_t)f2bf(q[j].x * inv) | ((uint32_t)f2bf(q[j].y * inv) << 16);
      pk.y = (uint32_t)f2bf(q[j].z * inv) | ((uint32_t)f2bf(q[j].w * inv) << 16);
      *(uint2*)((char*)a_lds + row * 512 + ((d * 2) ^ swz)) = pk;
    }
    if (t < 64) cnt[t] = 0;
  }
  __syncthreads();

  // ---- MFMA GEMM: A = en codes (L2), B = z rows (LDS) ----
  f32x4 acc[4][4];
#pragma unroll
  for (int mi = 0; mi < 4; mi++)
#pragma unroll
    for (int ni = 0; ni < 4; ni++) acc[mi][ni] = (f32x4){0.f, 0.f, 0.f, 0.f};

  const unsigned short* ep =
      en_b + ((size_t)(h * K) + w * 64 + arow) * DH + kg * 8;

#pragma unroll
  for (int ks = 0; ks < 8; ks++) {
    bf16x8 ef[4];
#pragma unroll
    for (int mi = 0; mi < 4; mi++)
      ef[mi] = *(const bf16x8*)(ep + (size_t)mi * 16 * DH + ks * 32);
    bf16x8 zf[4];
#pragma unroll
    for (int ni = 0; ni < 4; ni++) {
      const int rr = ni * 16 + arow;
      const int kb = (ks * 64) | (kg * 16);
      zf[ni] = *(const bf16x8*)((const char*)a_lds + rr * 512 +
                                (kb ^ ((rr & 7) << 4)));
    }
#pragma unroll
    for (int mi = 0; mi < 4; mi++)
#pragma unroll
      for (int ni = 0; ni < 4; ni++)
        acc[mi][ni] = __builtin_amdgcn_mfma_f32_16x16x32_bf16(ef[mi], zf[ni],
                                                              acc[mi][ni], 0, 0, 0);
  }

  // ---- pass 1: e = exp(sc*logit) in place; per-lane {max, 2nd-max, col, sum} ----
  const float sc = scales[h];
  float m1[4], m2[4], es[4]; int c1[4];
#pragma unroll
  for (int ni = 0; ni < 4; ni++) {
    m1[ni] = 0.0f; m2[ni] = 0.0f; es[ni] = 0.0f; c1[ni] = 1 << 30;
  }
#pragma unroll
  for (int mi = 0; mi < 4; mi++)
#pragma unroll
    for (int ni = 0; ni < 4; ni++)
#pragma unroll
      for (int q = 0; q < 4; q++) {
        const float e = __expf(sc * acc[mi][ni][q]);
        acc[mi][ni][q] = e;
        const int code = w * 64 + mi * 16 + kg * 4 + q;
        if (e > m1[ni]) { m2[ni] = m1[ni]; m1[ni] = e; c1[ni] = code; }
        else            m2[ni] = fmaxf(m2[ni], e);
        es[ni] += e;
      }
  // combine over kg (masks 16, 32)
#pragma unroll
  for (int m = 16; m < 64; m <<= 1) {
#pragma unroll
    for (int ni = 0; ni < 4; ni++) {
      const float om1 = __shfl_xor(m1[ni], m);
      const float om2 = __shfl_xor(m2[ni], m);
      const int   oc  = __shfl_xor(c1[ni], m);
      const float nm2 = fmaxf(fmaxf(m2[ni], om2), fminf(m1[ni], om1));
      if (om1 > m1[ni] || (om1 == m1[ni] && oc < c1[ni])) { m1[ni] = om1; c1[ni] = oc; }
      m2[ni] = nm2;
      es[ni] += __shfl_xor(es[ni], m);
    }
  }
  if (kg == 0) {
#pragma unroll
    for (int ni = 0; ni < 4; ni++) {
      const int r = ni * 16 + arow;
      wredm[w][r] = m1[ni];
      wred2[w][r] = m2[ni];
      wcols[w][r] = c1[ni];
      wreds[w][r] = es[ni];
    }
  }
  __syncthreads();
  if (t < 64) {
    float a1 = 0.0f, a2 = 0.0f, s = 0.0f; int c = 1 << 30;
#pragma unroll
    for (int ww = 0; ww < 8; ww++) {
      const float vm = wredm[ww][t];
      const float v2 = wred2[ww][t];
      const int   vc = wcols[ww][t];
      const float n2 = fmaxf(fmaxf(a2, v2), fminf(a1, vm));
      if (vm > a1 || (vm == a1 && vc < c)) { a1 = vm; c = vc; }
      a2 = n2;
      s += wreds[ww][t];
    }
    gmx[t] = a1; gcol[t] = c; Srec[t] = 1.0f / s;
    flagd[t] = (a2 >= a1 * CTH) ? 1 : 0;       // 2nd max within TAU -> refine
  }
  __syncthreads();

  // ---- pass 2: avg_probs partials -> LDS (wave-exclusive) + rare cand scan ----
  {
    float rs[4], th[4]; int fl[4];
#pragma unroll
    for (int ni = 0; ni < 4; ni++) {
      const int r = ni * 16 + arow;
      rs[ni] = Srec[r];
      th[ni] = gmx[r] * CTH;
      fl[ni] = flagd[r];
    }
#pragma unroll
    for (int mi = 0; mi < 4; mi++)
#pragma unroll
      for (int q = 0; q < 4; q++) {
        float vs = 0.0f;
#pragma unroll
        for (int ni = 0; ni < 4; ni++) vs = fmaf(acc[mi][ni][q], rs[ni], vs);
        vs += __shfl_xor(vs, 1);
        vs += __shfl_xor(vs, 2);
        vs += __shfl_xor(vs, 4);
        vs += __shfl_xor(vs, 8);
        if (arow == 0) avg_lds[w * 64 + mi * 16 + kg * 4 + q] = vs;
      }
    if (fl[0] | fl[1] | fl[2] | fl[3]) {
#pragma unroll
      for (int mi = 0; mi < 4; mi++)
#pragma unroll
        for (int ni = 0; ni < 4; ni++)
#pragma unroll
          for (int q = 0; q < 4; q++) {
            if (fl[ni] && acc[mi][ni][q] >= th[ni]) {
              const int r = ni * 16 + arow;
              const int p = atomicAdd(&cnt[r], 1);
              if (p < CMAX)
                cand[r][p] = (unsigned short)(w * 64 + mi * 16 + kg * 4 + q);
            }
          }
    }
  }
  __syncthreads();

  // ---- refine: exact fp32 dot for flagged rows (64-lane cooperative) ----
  for (int i = 0; i < 8; i++) {
    const int r = w * 8 + i;
    int c = cnt[r];
    int best;
    if (c <= 1) {
      best = gcol[r];
    } else {
      if (c > CMAX) c = CMAX;
      const float nrm = norms[r];
      const float4 zq = *(const float4*)(z_e + (size_t)(bbase + r) * (H * DH) +
                                         h * DH + l * 4);
      const float zn0 = zq.x / nrm, zn1 = zq.y / nrm,
                  zn2 = zq.z / nrm, zn3 = zq.w / nrm;
      float bv = -INFINITY; int bi = 1 << 30;
      for (int j = 0; j < c; j++) {
        const int cd = cand[r][j];
        const float4 eq = *(const float4*)(en_f + ((size_t)(h * K) + cd) * DH + l * 4);
        float d0 = fmaf(zn0, eq.x, fmaf(zn1, eq.y, fmaf(zn2, eq.z, zn3 * eq.w)));
#pragma unroll
        for (int m = 1; m < 64; m <<= 1) d0 += __shfl_xor(d0, m);
        if (d0 > bv || (d0 == bv && cd < bi)) { bv = d0; bi = cd; }
      }
      best = bi;
    }
    if (l == 0) fidx[r] = best;
  }
  __syncthreads();

  if (t < 64) idx_ws[(size_t)(bbase + t) * H + h] = fidx[t];

  // ---- one fire-and-forget global atomic per thread for avg_probs ----
  {
    float* ap = avgp + (blockIdx.x & (NREP - 1)) * (H * K) + h * K;
    atomicAdd(&ap[t], avg_lds[t]);
  }

  // ---- batched z_q gather: 8 rows/wave, all loads in flight ----
  {
    int ridx[8];
#pragma unroll
    for (int i = 0; i < 8; i++) ridx[i] = fidx[w * 8 + i];
    float4 gv[8];
#pragma unroll
    for (int i = 0; i < 8; i++)
      gv[i] = *(const float4*)(emb + ((size_t)(h * K) + ridx[i]) * DH + l * 4);
#pragma unroll
    for (int i = 0; i < 8; i++)
      *(float4*)(outq + (size_t)(bbase + w * 8 + i) * (H * DH) + h * DH + l * 4) =
          gv[i];
  }
}

// combined = ((idx0*512 + idx1)*512 + idx2)*512 + idx3 with int32 wraparound.
__global__ __launch_bounds__(256) void vq_combined(const int* __restrict__ idx_ws,
                                                   float* __restrict__ out_comb) {
  const int b = blockIdx.x * 256 + threadIdx.x;
  if (b < BT) {
    const int* p = idx_ws + (size_t)b * H;
    uint32_t cv = (uint32_t)p[0];
    cv = cv * 512u + (uint32_t)p[1];
    cv = cv * 512u + (uint32_t)p[2];
    cv = cv * 512u + (uint32_t)p[3];
    out_comb[b] = (float)(int32_t)cv;
  }
}

__global__ __launch_bounds__(256) void vq_perp(const float* __restrict__ avgp,
                                               float* __restrict__ out_perp) {
  const int t = threadIdx.x;
  float sh[H] = {0.f, 0.f, 0.f, 0.f};
  for (int i = t; i < H * K; i += 256) {
    const int h = i >> 9;
    float a = 0.0f;
#pragma unroll
    for (int c = 0; c < NREP; c++) a += avgp[c * (H * K) + i];
    a /= 65536.0f;
    sh[h] += a * logf(a + EPSL);
  }
  __shared__ float red[4][H];
#pragma unroll
  for (int h = 0; h < H; h++) {
    float s = sh[h];
#pragma unroll
    for (int m = 1; m < 64; m <<= 1) s += __shfl_xor(s, m);
    if ((t & 63) == 0) red[t >> 6][h] = s;
  }
  __syncthreads();
  if (t == 0) {
    float p = 0.0f;
#pragma unroll
    for (int h = 0; h < H; h++) {
      const float s = red[0][h] + red[1][h] + red[2][h] + red[3][h];
      p += expf(-s);
    }
    out_perp[0] = p * 0.25f;
  }
}

extern "C" void kernel_launch(void* const* d_in, const int* in_sizes, int n_in,
                              void* d_out, int out_size, void* d_ws, size_t ws_size,
                              hipStream_t stream) {
  const float* z_e    = (const float*)d_in[0];
  const float* emb    = (const float*)d_in[1];
  const float* scales = (const float*)d_in[2];
  float* out = (float*)d_out;

  float*          en_f   = (float*)d_ws;                        // 524288
  unsigned short* en_b   = (unsigned short*)(en_f + (size_t)H * K * DH);
  float*          avgp   = (float*)(en_b + (size_t)H * K * DH); // NREP*2048
  int*            idx_ws = (int*)(avgp + NREP * H * K);         // 262144

  hipLaunchKernelGGL(vq_prep, dim3(H * K), dim3(256), 0, stream,
                     emb, en_f, en_b, avgp);
  hipLaunchKernelGGL(vq_main, dim3(BT / 64, H), dim3(512), 0, stream,
                     z_e, emb, scales, en_f, en_b, avgp, idx_ws, out);
  hipLaunchKernelGGL(vq_combined, dim3(BT / 256), dim3(256), 0, stream,
                     idx_ws, out + (size_t)BT * H * DH);
  hipLaunchKernelGGL(vq_perp, dim3(1), dim3(256), 0, stream,
                     avgp, out + (size_t)BT * H * DH + BT);
}

// Round 9
// 282.370 us; speedup vs baseline: 1.3524x; 1.0523x over previous
//
#include <hip/hip_runtime.h>
#include <stdint.h>
#include <math.h>

#define BT   65536
#define H    4
#define K    512
#define DH   256
#define EPSN 1e-12f
#define EPSL 1e-10f
#define TAU  0.03f
#define CTH  0.970446f      // exp(-TAU)
#define CMAX 16
#define NREP 8              // avg_probs accumulator replicas

typedef short bf16x8 __attribute__((ext_vector_type(8)));
typedef float f32x4  __attribute__((ext_vector_type(4)));

__device__ inline unsigned short f2bf(float f) {
  uint32_t u = __builtin_bit_cast(uint32_t, f);
  u += 0x7fffu + ((u >> 16) & 1u);
  return (unsigned short)(u >> 16);
}

// RNE pack of two f32 -> packed 2xbf16 in one v_cvt_pk_bf16_f32.
__device__ inline uint32_t pack_bf2(float lo, float hi) {
  uint32_t r;
  asm("v_cvt_pk_bf16_f32 %0, %1, %2" : "=v"(r) : "v"(lo), "v"(hi));
  return r;
}

// ---------------------------------------------------------------------------
// ws layout (float slots):
//   en_f  : [H][K][DH] fp32 normalized      524288
//   en_b  : [H][K][DH] bf16 normalized      131072 slots
//   avgp  : [NREP][H*K]                     16384
//   idx_ws: [BT][H] int                     262144
// ---------------------------------------------------------------------------

__global__ __launch_bounds__(256) void vq_prep(const float* __restrict__ emb,
                                               float* __restrict__ en_f,
                                               unsigned short* __restrict__ en_b,
                                               float* __restrict__ avgp) {
  const int hk = blockIdx.x;        // h*K + k
  const int t  = threadIdx.x;       // d
  const float v = emb[(size_t)hk * DH + t];
  float s = v * v;
#pragma unroll
  for (int m = 1; m < 64; m <<= 1) s += __shfl_xor(s, m);
  __shared__ float wsum[4];
  if ((t & 63) == 0) wsum[t >> 6] = s;
  __syncthreads();
  const float tot = wsum[0] + wsum[1] + wsum[2] + wsum[3];
  const float n   = fmaxf(sqrtf(tot), EPSN);
  const float vn  = v / n;
  en_f[(size_t)hk * DH + t] = vn;
  en_b[(size_t)hk * DH + t] = f2bf(vn);
  if (t < NREP) avgp[t * (H * K) + hk] = 0.0f;
}

// Block: 64 b-rows x 512 codes for one h. 512 threads = 8 waves.
// Wave w owns codes [64w, 64w+64): acc[4][4]; code = 64w+16mi+4kg+q,
// zrow = 16ni + arow. 64 acc AGPR + ~64 VGPR = 128 unified -> 4 waves/SIMD cap.
// Argmax recovered purely from the candidate set: cnt==1 -> cand[0];
// cnt>1 -> exact fp32 refine (min-index tie-break).
__global__ __launch_bounds__(512, 4) void vq_main(
    const float* __restrict__ z_e, const float* __restrict__ emb,
    const float* __restrict__ scales,
    const float* __restrict__ en_f, const unsigned short* __restrict__ en_b,
    float* __restrict__ avgp, int* __restrict__ idx_ws,
    float* __restrict__ outq) {
  const int h     = blockIdx.y;
  const int bbase = blockIdx.x * 64;
  const int t     = threadIdx.x;
  const int w     = t >> 6;
  const int l     = t & 63;
  const int arow  = l & 15;
  const int kg    = l >> 4;                      // 0..3

  __shared__ unsigned short a_lds[64 * 256];     // 32 KiB z bf16, XOR-swizzled
  __shared__ float norms[64];
  __shared__ float wredm[8][64];                 // per-wave max
  __shared__ float wreds[8][64];                 // per-wave exp-sum
  __shared__ __align__(16) unsigned short cand[64][CMAX];
  __shared__ float thr[64];                      // gmx * CTH
  __shared__ float Srec[64];                     // 1/sum
  __shared__ int   cnt[64];
  __shared__ float avg_lds[512];                 // per-block avg_probs partial

  // ---- stage: load z row (8 lanes/row), L2-normalize (ref), bf16 -> LDS ----
  {
    const int row = t >> 3;                      // 0..63
    const int c8  = t & 7;
    const float* zp = z_e + (size_t)(bbase + row) * (H * DH) + h * DH;
    float4 q[8];
    float ss = 0.0f;
#pragma unroll
    for (int j = 0; j < 8; j++) {
      q[j] = *(const float4*)(zp + c8 * 4 + j * 32);
      ss += q[j].x * q[j].x + q[j].y * q[j].y + q[j].z * q[j].z + q[j].w * q[j].w;
    }
    ss += __shfl_xor(ss, 1);
    ss += __shfl_xor(ss, 2);
    ss += __shfl_xor(ss, 4);
    const float n   = fmaxf(sqrtf(ss), EPSN);
    const float inv = 1.0f / n;
    if (c8 == 0) norms[row] = n;
    const int swz = (row & 7) << 4;
#pragma unroll
    for (int j = 0; j < 8; j++) {
      const int d = c8 * 4 + j * 32;
      uint2 pk;
      pk.x = pack_bf2(q[j].x * inv, q[j].y * inv);
      pk.y = pack_bf2(q[j].z * inv, q[j].w * inv);
      *(uint2*)((char*)a_lds + row * 512 + ((d * 2) ^ swz)) = pk;
    }
    if (t < 64) cnt[t] = 0;
  }
  __syncthreads();

  // ---- MFMA GEMM: A = en codes (L2), B = z rows (LDS) ----
  f32x4 acc[4][4];
#pragma unroll
  for (int mi = 0; mi < 4; mi++)
#pragma unroll
    for (int ni = 0; ni < 4; ni++) acc[mi][ni] = (f32x4){0.f, 0.f, 0.f, 0.f};

  const unsigned short* ep =
      en_b + ((size_t)(h * K) + w * 64 + arow) * DH + kg * 8;

#pragma unroll
  for (int ks = 0; ks < 8; ks++) {
    bf16x8 ef[4];
#pragma unroll
    for (int mi = 0; mi < 4; mi++)
      ef[mi] = *(const bf16x8*)(ep + (size_t)mi * 16 * DH + ks * 32);
    bf16x8 zf[4];
#pragma unroll
    for (int ni = 0; ni < 4; ni++) {
      const int rr = ni * 16 + arow;
      const int kb = (ks * 64) | (kg * 16);
      zf[ni] = *(const bf16x8*)((const char*)a_lds + rr * 512 +
                                (kb ^ ((rr & 7) << 4)));
    }
#pragma unroll
    for (int mi = 0; mi < 4; mi++)
#pragma unroll
      for (int ni = 0; ni < 4; ni++)
        acc[mi][ni] = __builtin_amdgcn_mfma_f32_16x16x32_bf16(ef[mi], zf[ni],
                                                              acc[mi][ni], 0, 0, 0);
  }

  // ---- pass 1: e = exp(sc*logit) in place; per-lane {max, sum} only ----
  const float sc = scales[h];
  float m1[4], es[4];
#pragma unroll
  for (int ni = 0; ni < 4; ni++) { m1[ni] = 0.0f; es[ni] = 0.0f; }
#pragma unroll
  for (int mi = 0; mi < 4; mi++)
#pragma unroll
    for (int ni = 0; ni < 4; ni++)
#pragma unroll
      for (int q = 0; q < 4; q++) {
        const float e = __expf(sc * acc[mi][ni][q]);
        acc[mi][ni][q] = e;
        m1[ni] = fmaxf(m1[ni], e);
        es[ni] += e;
      }
  // combine over kg (masks 16, 32)
#pragma unroll
  for (int m = 16; m < 64; m <<= 1) {
#pragma unroll
    for (int ni = 0; ni < 4; ni++) {
      m1[ni] = fmaxf(m1[ni], __shfl_xor(m1[ni], m));
      es[ni] += __shfl_xor(es[ni], m);
    }
  }
  if (kg == 0) {
#pragma unroll
    for (int ni = 0; ni < 4; ni++) {
      const int r = ni * 16 + arow;
      wredm[w][r] = m1[ni];
      wreds[w][r] = es[ni];
    }
  }
  __syncthreads();
  if (t < 64) {
    float a1 = 0.0f, s = 0.0f;
#pragma unroll
    for (int ww = 0; ww < 8; ww++) {
      a1 = fmaxf(a1, wredm[ww][t]);
      s += wreds[ww][t];
    }
    thr[t] = a1 * CTH; Srec[t] = 1.0f / s;
  }
  __syncthreads();

  // ---- pass 2: avg_probs partials -> LDS + candidate scan (e >= thr) ----
  {
    float rs[4], th[4];
#pragma unroll
    for (int ni = 0; ni < 4; ni++) {
      const int r = ni * 16 + arow;
      rs[ni] = Srec[r];
      th[ni] = thr[r];
    }
#pragma unroll
    for (int mi = 0; mi < 4; mi++)
#pragma unroll
      for (int q = 0; q < 4; q++) {
        float vs = 0.0f;
#pragma unroll
        for (int ni = 0; ni < 4; ni++) {
          const float e = acc[mi][ni][q];
          vs = fmaf(e, rs[ni], vs);
          if (e >= th[ni]) {
            const int r = ni * 16 + arow;
            const int p = atomicAdd(&cnt[r], 1);
            if (p < CMAX)
              cand[r][p] = (unsigned short)(w * 64 + mi * 16 + kg * 4 + q);
          }
        }
        vs += __shfl_xor(vs, 1);
        vs += __shfl_xor(vs, 2);
        vs += __shfl_xor(vs, 4);
        vs += __shfl_xor(vs, 8);
        if (arow == 0) avg_lds[w * 64 + mi * 16 + kg * 4 + q] = vs;
      }
  }
  __syncthreads();

  // ---- one fire-and-forget global atomic per thread for avg_probs ----
  {
    float* ap = avgp + (blockIdx.x & (NREP - 1)) * (H * K) + h * K;
    atomicAdd(&ap[t], avg_lds[t]);
  }

  // ---- refine + idx write + gather, fully wave-local (no more barriers) ----
  int best8[8];
#pragma unroll
  for (int i = 0; i < 8; i++) {
    const int r = w * 8 + i;
    int c = cnt[r];
    int best;
    if (c <= 1) {
      best = cand[r][0];                 // cnt>=1 always: max itself passes thr
    } else {
      if (c > CMAX) c = CMAX;
      const float nrm = norms[r];
      const float4 zq = *(const float4*)(z_e + (size_t)(bbase + r) * (H * DH) +
                                         h * DH + l * 4);
      const float zn0 = zq.x / nrm, zn1 = zq.y / nrm,
                  zn2 = zq.z / nrm, zn3 = zq.w / nrm;
      float bv = -INFINITY; int bi = 1 << 30;
      for (int j = 0; j < c; j++) {
        const int cd = cand[r][j];
        const float4 eq = *(const float4*)(en_f + ((size_t)(h * K) + cd) * DH + l * 4);
        float d0 = fmaf(zn0, eq.x, fmaf(zn1, eq.y, fmaf(zn2, eq.z, zn3 * eq.w)));
#pragma unroll
        for (int m = 1; m < 64; m <<= 1) d0 += __shfl_xor(d0, m);
        if (d0 > bv || (d0 == bv && cd < bi)) { bv = d0; bi = cd; }
      }
      best = bi;                         // lane-uniform
    }
    best8[i] = best;
    if (l == i) idx_ws[(size_t)(bbase + r) * H + h] = best;
  }

  // ---- batched z_q gather: 8 rows/wave, all loads in flight ----
  {
    float4 gv[8];
#pragma unroll
    for (int i = 0; i < 8; i++)
      gv[i] = *(const float4*)(emb + ((size_t)(h * K) + best8[i]) * DH + l * 4);
#pragma unroll
    for (int i = 0; i < 8; i++)
      *(float4*)(outq + (size_t)(bbase + w * 8 + i) * (H * DH) + h * DH + l * 4) =
          gv[i];
  }
}

// combined = ((idx0*512 + idx1)*512 + idx2)*512 + idx3 with int32 wraparound.
__global__ __launch_bounds__(256) void vq_combined(const int* __restrict__ idx_ws,
                                                   float* __restrict__ out_comb) {
  const int b = blockIdx.x * 256 + threadIdx.x;
  if (b < BT) {
    const int* p = idx_ws + (size_t)b * H;
    uint32_t cv = (uint32_t)p[0];
    cv = cv * 512u + (uint32_t)p[1];
    cv = cv * 512u + (uint32_t)p[2];
    cv = cv * 512u + (uint32_t)p[3];
    out_comb[b] = (float)(int32_t)cv;
  }
}

__global__ __launch_bounds__(256) void vq_perp(const float* __restrict__ avgp,
                                               float* __restrict__ out_perp) {
  const int t = threadIdx.x;
  float sh[H] = {0.f, 0.f, 0.f, 0.f};
  for (int i = t; i < H * K; i += 256) {
    const int h = i >> 9;
    float a = 0.0f;
#pragma unroll
    for (int c = 0; c < NREP; c++) a += avgp[c * (H * K) + i];
    a /= 65536.0f;
    sh[h] += a * logf(a + EPSL);
  }
  __shared__ float red[4][H];
#pragma unroll
  for (int h = 0; h < H; h++) {
    float s = sh[h];
#pragma unroll
    for (int m = 1; m < 64; m <<= 1) s += __shfl_xor(s, m);
    if ((t & 63) == 0) red[t >> 6][h] = s;
  }
  __syncthreads();
  if (t == 0) {
    float p = 0.0f;
#pragma unroll
    for (int h = 0; h < H; h++) {
      const float s = red[0][h] + red[1][h] + red[2][h] + red[3][h];
      p += expf(-s);
    }
    out_perp[0] = p * 0.25f;
  }
}

extern "C" void kernel_launch(void* const* d_in, const int* in_sizes, int n_in,
                              void* d_out, int out_size, void* d_ws, size_t ws_size,
                              hipStream_t stream) {
  const float* z_e    = (const float*)d_in[0];
  const float* emb    = (const float*)d_in[1];
  const float* scales = (const float*)d_in[2];
  float* out = (float*)d_out;

  float*          en_f   = (float*)d_ws;                        // 524288
  unsigned short* en_b   = (unsigned short*)(en_f + (size_t)H * K * DH);
  float*          avgp   = (float*)(en_b + (size_t)H * K * DH); // NREP*2048
  int*            idx_ws = (int*)(avgp + NREP * H * K);         // 262144

  hipLaunchKernelGGL(vq_prep, dim3(H * K), dim3(256), 0, stream,
                     emb, en_f, en_b, avgp);
  hipLaunchKernelGGL(vq_main, dim3(BT / 64, H), dim3(512), 0, stream,
                     z_e, emb, scales, en_f, en_b, avgp, idx_ws, out);
  hipLaunchKernelGGL(vq_combined, dim3(BT / 256), dim3(256), 0, stream,
                     idx_ws, out + (size_t)BT * H * DH);
  hipLaunchKernelGGL(vq_perp, dim3(1), dim3(256), 0, stream,
                     avgp, out + (size_t)BT * H * DH + BT);
}